// Round 2
// 70.247 us; speedup vs baseline: 1.0014x; 1.0014x over previous
//
#include <hip/hip_runtime.h>
#include <math.h>

// 4-qubit, 2-layer circuit — CLOSED FORM via Heisenberg/Pauli backpropagation.
// NOT cyclically symmetric (CNOT ring order matters); each wire derived
// independently. Images through the reversed CNOT ring T:
//   T(Z0)=Z1Z2Z3 T(Z1)=Z0Z1 T(Z2)=Z0Z1Z2 T(Z3)=Z0Z1Z2Z3
//   T(X0)=X0X1   T(X1)=X1X2 T(X2)=X2X3   T(X3)=X0X1X3   <- note X1!
// Evaluate on RX product state: <X>=0, <Z_v>=z_v=cos n_v, <Y_v>=-y_v=-sin n_v.
// All surviving terms verified term-by-term vs direct single-angle Heisenberg
// probes + weights=0 GF(2) parity + |+>^4 + |1111> global checks.
//
// <Z0> = C10C03[C01C02 z0z1z3 + C01S02 y2y3 - S01S02 z0y1z2y3]
//      + S10   [C00S01 y0y1   + S00C01 y1y2z3 - S00S01 z0z2z3]
// <Z1> = C11[C00C01 z0z2z3 + C00S01 y1y2z3 + S00C01 y0y1]
//      + S11S02[C01 z0y1y2 - S01 z2]
// <Z2> = C12[C00C01C02 z1z3 + C00C01S02 z0y2y3 - C00S01S02 y1z2y3
//            - S00S01C02 y0z1y2]
//      + S12S03[C02 z0z1y2y3 - S02 z3]
// <Z3> = C13C03[C00C01C02 z0z2 + C00S01C02 y1y2 + S00C01C02 y0y1z3
//               + S00S01S02 y0z1z2y3]
//      + S13S03[C00C01 y0z1y2z3 - S00S01 z1]
// out_w = (1 + <Z_w>)/2
//
// This revision: 4 elements/thread via 4 stride-nT coalesced streams.
// Rationale: weight trig (8 sincos) + 22 coefficient products are
// batch-uniform but were recomputed by every thread — amortize 4x, and the
// 4 in-flight loads hide HBM latency under the uniform computation.

struct Coef {
    float K01, K02, K03, K04, K05, K06;
    float K11, K12, K13, K14, K15;
    float K21, K22, K23, K24, K25, K26;
    float K31, K32, K33, K34, K35, K36;
};

__device__ __forceinline__ Coef make_coef(const float* __restrict__ weights) {
    float C0[4], S0[4], C1[4], S1[4];
#pragma unroll
    for (int v = 0; v < 4; v++) {
        __sincosf(weights[v],     &S0[v], &C0[v]);
        __sincosf(weights[4 + v], &S1[v], &C1[v]);
    }

    Coef K;
    float A0 = C1[0] * C0[3];
    K.K01 = A0 * C0[1] * C0[2]; K.K02 = A0 * C0[1] * S0[2]; K.K03 = -A0 * S0[1] * S0[2];
    K.K04 = S1[0] * C0[0] * S0[1]; K.K05 = S1[0] * S0[0] * C0[1]; K.K06 = -S1[0] * S0[0] * S0[1];

    K.K11 = C1[1] * C0[0] * C0[1]; K.K12 = C1[1] * C0[0] * S0[1]; K.K13 = C1[1] * S0[0] * C0[1];
    float B1 = S1[1] * S0[2];
    K.K14 = B1 * C0[1]; K.K15 = -B1 * S0[1];

    float A2 = C1[2] * C0[0];
    K.K21 = A2 * C0[1] * C0[2]; K.K22 = A2 * C0[1] * S0[2]; K.K23 = -A2 * S0[1] * S0[2];
    K.K24 = -C1[2] * S0[0] * S0[1] * C0[2];
    float B2 = S1[2] * S0[3];
    K.K25 = B2 * C0[2]; K.K26 = -B2 * S0[2];

    float A3 = C1[3] * C0[3] * C0[2];
    K.K31 = A3 * C0[0] * C0[1]; K.K32 = A3 * C0[0] * S0[1]; K.K33 = A3 * S0[0] * C0[1];
    K.K34 = C1[3] * C0[3] * S0[0] * S0[1] * S0[2];
    float B3 = S1[3] * S0[3];
    K.K35 = B3 * C0[0] * C0[1]; K.K36 = -B3 * S0[0] * S0[1];
    return K;
}

__device__ __forceinline__ float4 qc_eval(const Coef& K, const float4 nv) {
    float z0, z1, z2, z3, y0, y1, y2, y3;
    __sincosf(nv.x, &y0, &z0);
    __sincosf(nv.y, &y1, &z1);
    __sincosf(nv.z, &y2, &z2);
    __sincosf(nv.w, &y3, &z3);

    // Shared pair products.
    float z01 = z0 * z1, z02 = z0 * z2, z12 = z1 * z2, z13 = z1 * z3;
    float y01 = y0 * y1, y12 = y1 * y2, y23 = y2 * y3;
    float y02 = y0 * y2, y13 = y1 * y3, y03 = y0 * y3;

    float Z0 = K.K01 * (z01 * z3);
    Z0 = __builtin_fmaf(K.K02, y23, Z0);
    Z0 = __builtin_fmaf(K.K03, z02 * y13, Z0);
    Z0 = __builtin_fmaf(K.K04, y01, Z0);
    Z0 = __builtin_fmaf(K.K05, y12 * z3, Z0);
    Z0 = __builtin_fmaf(K.K06, z02 * z3, Z0);

    float Z1 = K.K11 * (z02 * z3);
    Z1 = __builtin_fmaf(K.K12, y12 * z3, Z1);
    Z1 = __builtin_fmaf(K.K13, y01, Z1);
    Z1 = __builtin_fmaf(K.K14, z0 * y12, Z1);
    Z1 = __builtin_fmaf(K.K15, z2, Z1);

    float Z2 = K.K21 * z13;
    Z2 = __builtin_fmaf(K.K22, z0 * y23, Z2);
    Z2 = __builtin_fmaf(K.K23, y13 * z2, Z2);
    Z2 = __builtin_fmaf(K.K24, y02 * z1, Z2);
    Z2 = __builtin_fmaf(K.K25, z01 * y23, Z2);
    Z2 = __builtin_fmaf(K.K26, z3, Z2);

    float Z3 = K.K31 * z02;
    Z3 = __builtin_fmaf(K.K32, y12, Z3);
    Z3 = __builtin_fmaf(K.K33, y01 * z3, Z3);
    Z3 = __builtin_fmaf(K.K34, y03 * z12, Z3);
    Z3 = __builtin_fmaf(K.K35, y02 * z13, Z3);
    Z3 = __builtin_fmaf(K.K36, z1, Z3);

    return make_float4(__builtin_fmaf(0.5f, Z0, 0.5f), __builtin_fmaf(0.5f, Z1, 0.5f),
                       __builtin_fmaf(0.5f, Z2, 0.5f), __builtin_fmaf(0.5f, Z3, 0.5f));
}

__global__ __launch_bounds__(256) void qc_kernel(const float* __restrict__ noise,
                                                 const float* __restrict__ weights,
                                                 float* __restrict__ out, int B, int nT) {
    int t = blockIdx.x * blockDim.x + threadIdx.x;
    if (t >= nT) return;

    const float4* __restrict__ nin = reinterpret_cast<const float4*>(noise);
    float4* __restrict__ oout = reinterpret_cast<float4*>(out);

    int b3 = t + 3 * nT;
    if (b3 < B) {
        // Hot path (B % 4 == 0 and full tile): issue all 4 coalesced loads
        // first so HBM latency hides under the uniform coefficient compute.
        float4 n0 = nin[t];
        float4 n1 = nin[t + nT];
        float4 n2 = nin[t + 2 * nT];
        float4 n3 = nin[b3];
        Coef K = make_coef(weights);
        float4 r0 = qc_eval(K, n0);
        float4 r1 = qc_eval(K, n1);
        float4 r2 = qc_eval(K, n2);
        float4 r3 = qc_eval(K, n3);
        oout[t] = r0;
        oout[t + nT] = r1;
        oout[t + 2 * nT] = r2;
        oout[b3] = r3;
    } else {
        Coef K = make_coef(weights);
#pragma unroll
        for (int k = 0; k < 4; ++k) {
            int b = t + k * nT;
            if (b < B) oout[b] = qc_eval(K, nin[b]);
        }
    }
}

extern "C" void kernel_launch(void* const* d_in, const int* in_sizes, int n_in,
                              void* d_out, int out_size, void* d_ws, size_t ws_size,
                              hipStream_t stream) {
    const float* noise   = (const float*)d_in[0];   // (B, 4)
    const float* weights = (const float*)d_in[1];   // (2, 4)
    float* out = (float*)d_out;                     // (B, 4)
    int B = in_sizes[0] / 4;

    int nT = (B + 3) / 4;                           // threads, 4 elements each
    qc_kernel<<<(nT + 255) / 256, 256, 0, stream>>>(noise, weights, out, B, nT);
}